// Round 5
// baseline (299.098 us; speedup 1.0000x reference)
//
#include <hip/hip_runtime.h>
#include <math.h>

#define MEMSZ 16384
#define NCTX  16453   // MEM + 5 + 64
#define MAXT  16      // fast-path unroll bound (num_steps in harness = 16)
#define LOGCAP 64     // ws log stride per row (slow path supports T<=64)
#define TPB   64      // one wave per block; LDS arrays sized for this

// ---- soft-gate helpers (exact float32 replication of the reference) ----
__device__ __forceinline__ float sigmoidf_(float x) {
    return 1.0f / (1.0f + __expf(-x));
}
__device__ __forceinline__ float siluf_(float x) {
    return x * sigmoidf_(x);
}
__device__ __forceinline__ float silu_thr(float x) {
    float d = 20.0f * x;
    return (siluf_(d + 10.0f) - siluf_(d - 10.0f)) * 0.05f;
}
__device__ __forceinline__ float eq_gate_d(float diff) {
    return silu_thr(diff + 0.5f) * silu_thr(0.5f - diff);
}

__device__ __forceinline__ float clipaddr(float x) {
    return fminf(fmaxf(x, 0.0f), (float)(NCTX - 1));
}

// register/context value for slot r = ai - MEMSZ (r in [0,68])
__device__ __forceinline__ float regval(int r, float pcv, float spv, float bpv,
                                        float axv, float olf,
                                        const float* __restrict__ orow) {
    return (r == 0) ? pcv
         : (r == 1) ? spv
         : (r == 2) ? bpv
         : (r == 3) ? axv
         : (r == 4) ? olf
                    : orow[r - 5];
}

// NO ARRAYS: explicit gate sequence, same accumulation order as the
// reference loop (opv order 1,2,9..15,3..8) so results stay bitwise equal.
__device__ __forceinline__ float pop_of(float opc) {
    float pop = 0.0f;
    pop += eq_gate_d(opc - 9.0f);
    pop += eq_gate_d(opc - 10.0f);
    pop += eq_gate_d(opc - 11.0f);
    pop += eq_gate_d(opc - 12.0f);
    pop += eq_gate_d(opc - 13.0f);
    pop += eq_gate_d(opc - 14.0f);
    pop += eq_gate_d(opc - 15.0f);
    pop += eq_gate_d(opc - 3.0f);
    pop += eq_gate_d(opc - 4.0f);
    pop += eq_gate_d(opc - 5.0f);
    pop += eq_gate_d(opc - 6.0f);
    pop += eq_gate_d(opc - 7.0f);
    pop += eq_gate_d(opc - 8.0f);
    return pop;
}

__device__ __forceinline__ float step_update(float stv, float ax, float imm,
                                             float bp, float opc, float* pop_out) {
    float a = stv, bv = ax;
    float safeb = (fabsf(bv) < 1e-6f) ? 1e-6f : bv;
    float dv = a / safeb;
    float md = a - safeb * floorf(dv);
    float sh = fminf(fmaxf(bv, 0.0f), 31.0f);
    float eq = eq_gate_d(a - bv);
    float lt = sigmoidf_(20.0f * (bv - a - 0.5f));
    float gt = sigmoidf_(20.0f * (a - bv - 0.5f));
    float gsum = 0.0f, acc = 0.0f, pop = 0.0f, g;
    g = eq_gate_d(opc - 1.0f);  gsum += g; acc += g * imm;
    g = eq_gate_d(opc - 2.0f);  gsum += g; acc += g * (bp + imm);
    g = eq_gate_d(opc - 9.0f);  gsum += g; acc += g * (a + bv);          pop += g;
    g = eq_gate_d(opc - 10.0f); gsum += g; acc += g * (a - bv);          pop += g;
    g = eq_gate_d(opc - 11.0f); gsum += g; acc += g * (a * bv);          pop += g;
    g = eq_gate_d(opc - 12.0f); gsum += g; acc += g * dv;                pop += g;
    g = eq_gate_d(opc - 13.0f); gsum += g; acc += g * md;                pop += g;
    g = eq_gate_d(opc - 14.0f); gsum += g; acc += g * (a * exp2f(sh));   pop += g;
    g = eq_gate_d(opc - 15.0f); gsum += g; acc += g * (a * exp2f(-sh));  pop += g;
    g = eq_gate_d(opc - 3.0f);  gsum += g; acc += g * eq;                pop += g;
    g = eq_gate_d(opc - 4.0f);  gsum += g; acc += g * (1.0f - eq);       pop += g;
    g = eq_gate_d(opc - 5.0f);  gsum += g; acc += g * lt;                pop += g;
    g = eq_gate_d(opc - 6.0f);  gsum += g; acc += g * gt;                pop += g;
    g = eq_gate_d(opc - 7.0f);  gsum += g; acc += g * (1.0f - gt);       pop += g;
    g = eq_gate_d(opc - 8.0f);  gsum += g; acc += g * (1.0f - lt);       pop += g;
    *pop_out = pop;
    return acc + (1.0f - gsum) * ax;
}

// ---- bulk copy: memory -> d_out ----
__global__ void copy_kernel(const float4* __restrict__ src,
                            float4* __restrict__ dst, int n4) {
    int i = blockIdx.x * blockDim.x + threadIdx.x;
    if (i < n4) dst[i] = src[i];
}

// ---- per-row sim: reads PRISTINE input mem, writes results into out ----
// Per-row state lives in EXPLICIT LDS (rounds 2-4 lesson: local arrays kept
// landing in scratch; LDS makes spilling impossible). Stride 17 = conflict-free.
__global__ void __launch_bounds__(TPB, 1)
sim_kernel(const float* __restrict__ mem,
           float* __restrict__ out,
           const float* __restrict__ outp,
           const float* __restrict__ ax_in,
           const int* __restrict__ pc_in,
           const int* __restrict__ sp_in,
           const int* __restrict__ bp_in,
           const int* __restrict__ ol_in,
           const int* __restrict__ nstep,
           int B, int* la, float* lv) {
    __shared__ float s_raw[TPB][MAXT + 1];
    __shared__ float s_spA[TPB][MAXT + 1];
    __shared__ int   s_tgt[TPB][MAXT + 1];
    __shared__ float s_svr[TPB][MAXT + 1];
    __shared__ float s_lvv[TPB][MAXT + 1];

    int tid = threadIdx.x;
    int b = blockIdx.x * TPB + tid;
    if (b >= B) return;

    const float* __restrict__ mrow = mem + (size_t)b * MEMSZ;
    float* __restrict__ wrow = out + (size_t)b * MEMSZ;
    const float* __restrict__ orow = outp + (size_t)b * 64;

    float pc0 = (float)pc_in[b];
    float sp0 = (float)sp_in[b];
    float bp0 = (float)bp_in[b];
    float ax0 = ax_in[b];
    float olf = (float)ol_in[b];
    int T = nstep[0];

    bool slow = (T > MAXT) || (T < 0);

    if (!slow) {
        // prefetch all instruction loads (pc chain is static) — 16 parallel
#pragma unroll
        for (int t = 0; t < MAXT; ++t) {
            if (t < T) {
                int ai = (int)clipaddr(pc0 + 8.0f * t);
                int ia = (ai < MEMSZ) ? ai : ai - MEMSZ;
                s_raw[tid][t] = mrow[ia];
            }
        }
        // pass A: opcode -> pop -> sp chain -> targets (ALU + LDS only)
        float spc = sp0;
#pragma unroll
        for (int t = 0; t < MAXT; ++t) {
            if (t < T) {
                int ai = (int)clipaddr(pc0 + 8.0f * t);
                int ia = (ai < MEMSZ) ? ai : ai - MEMSZ;
#pragma unroll
                for (int j = 0; j < MAXT; ++j)
                    if (j < t && s_tgt[tid][j] == ia) slow = true;  // RAW hazard
                float inst;
                if (ai < MEMSZ) {
                    inst = s_raw[tid][t];
                } else {
                    int r = ai - MEMSZ;
                    if (r == 3) slow = true;                        // needs ax chain
                    float cv = regval(r, pc0 + 8.0f * t, spc, bp0, 0.0f, olf, orow);
                    inst = 0.5f * (cv + s_raw[tid][t]);
                }
                float imm = floorf(inst * (1.0f / 256.0f));
                float opc = inst - imm * 256.0f;
                float popv = pop_of(opc);
                s_spA[tid][t] = spc;
                int si = (int)clipaddr(spc);
                s_tgt[tid][t] = (si < MEMSZ) ? si : si - MEMSZ;
                spc = spc + 8.0f * popv;
            }
        }
    }

    if (!slow) {
        // pass B: all stack-top loads in parallel
#pragma unroll
        for (int t = 0; t < MAXT; ++t)
            if (t < T) s_svr[tid][t] = mrow[s_tgt[tid][t]];
        // pass C: ax chain + experts + direct in-order writes
        float ax = ax0;
#pragma unroll
        for (int t = 0; t < MAXT; ++t) {
            if (t < T) {
                int ai = (int)clipaddr(pc0 + 8.0f * t);
                float inst;
                if (ai < MEMSZ) {
                    inst = s_raw[tid][t];
                } else {
                    int r = ai - MEMSZ;
                    float cv = regval(r, pc0 + 8.0f * t, s_spA[tid][t], bp0, ax, olf, orow);
                    inst = 0.5f * (cv + s_raw[tid][t]);
                }
                float imm = floorf(inst * (1.0f / 256.0f));
                float opc = inst - imm * 256.0f;
                float mtv = s_svr[tid][t];
                int tg = s_tgt[tid][t];
#pragma unroll
                for (int j = 0; j < MAXT; ++j)
                    if (j < t && s_tgt[tid][j] == tg) mtv = s_lvv[tid][j];  // overlay
                int si = (int)clipaddr(s_spA[tid][t]);
                float stv, wf;
                if (si < MEMSZ) {
                    stv = mtv; wf = 1.0f;
                } else {
                    int r = si - MEMSZ;
                    float cv = regval(r, pc0 + 8.0f * t, s_spA[tid][t], bp0, ax, olf, orow);
                    stv = 0.5f * (cv + mtv); wf = 0.5f;
                }
                float pop;
                float nax = step_update(stv, ax, imm, bp0, opc, &pop);
                float val = mtv + pop * wf * (nax - mtv);
                s_lvv[tid][t] = val;
                wrow[tg] = val;     // in-order per-thread stores: last write wins
                ax = nax;
            }
        }
    } else {
        // generic fully-sequential path (hazard rows / T > MAXT), ws-based log
        int*   lrow_a = la + (size_t)b * LOGCAP;
        float* lrow_v = lv + (size_t)b * LOGCAP;
        float pc = pc0, sp = sp0, ax = ax0;
        int Tc = (T > LOGCAP) ? LOGCAP : T;
        for (int t = 0; t < Tc; ++t) {
            int ai = (int)clipaddr(pc);
            int ia = (ai < MEMSZ) ? ai : ai - MEMSZ;
            float v = mrow[ia];
            for (int j = 0; j < t; ++j)
                if (lrow_a[j] == ia) v = lrow_v[j];
            float inst;
            if (ai < MEMSZ) {
                inst = v;
            } else {
                int r = ai - MEMSZ;
                float cv = regval(r, pc, sp, bp0, ax, olf, orow);
                inst = 0.5f * (cv + v);
            }
            float imm = floorf(inst * (1.0f / 256.0f));
            float opc = inst - imm * 256.0f;
            int si = (int)clipaddr(sp);
            int tg = (si < MEMSZ) ? si : si - MEMSZ;
            float mtv = mrow[tg];
            for (int j = 0; j < t; ++j)
                if (lrow_a[j] == tg) mtv = lrow_v[j];
            float stv, wf;
            if (si < MEMSZ) {
                stv = mtv; wf = 1.0f;
            } else {
                int r = si - MEMSZ;
                float cv = regval(r, pc, sp, bp0, ax, olf, orow);
                stv = 0.5f * (cv + mtv); wf = 0.5f;
            }
            float pop;
            float nax = step_update(stv, ax, imm, bp0, opc, &pop);
            float val = mtv + pop * wf * (nax - mtv);
            lrow_a[t] = tg;
            lrow_v[t] = val;
            wrow[tg] = val;        // in-order per-thread stores: last write wins
            sp = sp + 8.0f * pop;
            pc = pc + 8.0f;
            ax = nax;
        }
    }
}

extern "C" void kernel_launch(void* const* d_in, const int* in_sizes, int n_in,
                              void* d_out, int out_size, void* d_ws, size_t ws_size,
                              hipStream_t stream) {
    const float* memory = (const float*)d_in[0];
    const float* output = (const float*)d_in[1];
    const float* ax     = (const float*)d_in[2];
    const int*   pc     = (const int*)d_in[3];
    const int*   sp     = (const int*)d_in[4];
    const int*   bp     = (const int*)d_in[5];
    const int*   ol     = (const int*)d_in[6];
    const int*   ns     = (const int*)d_in[7];

    int B = in_sizes[0] / MEMSZ;
    int n4 = B * MEMSZ / 4;

    float* out = (float*)d_out;
    int* la = (int*)d_ws;
    float* lv = (float*)(la + (size_t)B * LOGCAP);

    hipLaunchKernelGGL(copy_kernel, dim3((n4 + 255) / 256), dim3(256), 0, stream,
                       (const float4*)memory, (float4*)out, n4);
    hipLaunchKernelGGL(sim_kernel, dim3((B + TPB - 1) / TPB), dim3(TPB), 0, stream,
                       memory, out, output, ax, pc, sp, bp, ol, ns, B, la, lv);
}

// Round 6
// 278.694 us; speedup vs baseline: 1.0732x; 1.0732x over previous
//
#include <hip/hip_runtime.h>
#include <math.h>

#define MEMSZ 16384
#define NCTX  16453   // MEM + 5 + 64
#define MAXT  16      // fast-path unroll bound (num_steps in harness = 16)
#define TPB   64      // one wave per block; LDS arrays sized for this

// ---- soft-gate helpers (exact float32 replication of the reference) ----
__device__ __forceinline__ float sigmoidf_(float x) {
    return 1.0f / (1.0f + __expf(-x));
}
__device__ __forceinline__ float siluf_(float x) {
    return x * sigmoidf_(x);
}
__device__ __forceinline__ float silu_thr(float x) {
    float d = 20.0f * x;
    return (siluf_(d + 10.0f) - siluf_(d - 10.0f)) * 0.05f;
}
__device__ __forceinline__ float eq_gate_d(float diff) {
    return silu_thr(diff + 0.5f) * silu_thr(0.5f - diff);
}

__device__ __forceinline__ float clipaddr(float x) {
    return fminf(fmaxf(x, 0.0f), (float)(NCTX - 1));
}

// register/context value for slot r = ai - MEMSZ (r in [0,68])
__device__ __forceinline__ float regval(int r, float pcv, float spv, float bpv,
                                        float axv, float olf,
                                        const float* __restrict__ orow) {
    return (r == 0) ? pcv
         : (r == 1) ? spv
         : (r == 2) ? bpv
         : (r == 3) ? axv
         : (r == 4) ? olf
                    : orow[r - 5];
}

// NO ARRAYS: explicit gate sequence, same accumulation order as the
// reference loop (opv order 1,2,9..15,3..8) so results stay bitwise equal.
__device__ __forceinline__ float pop_of(float opc) {
    float pop = 0.0f;
    pop += eq_gate_d(opc - 9.0f);
    pop += eq_gate_d(opc - 10.0f);
    pop += eq_gate_d(opc - 11.0f);
    pop += eq_gate_d(opc - 12.0f);
    pop += eq_gate_d(opc - 13.0f);
    pop += eq_gate_d(opc - 14.0f);
    pop += eq_gate_d(opc - 15.0f);
    pop += eq_gate_d(opc - 3.0f);
    pop += eq_gate_d(opc - 4.0f);
    pop += eq_gate_d(opc - 5.0f);
    pop += eq_gate_d(opc - 6.0f);
    pop += eq_gate_d(opc - 7.0f);
    pop += eq_gate_d(opc - 8.0f);
    return pop;
}

__device__ __forceinline__ float step_update(float stv, float ax, float imm,
                                             float bp, float opc, float* pop_out) {
    float a = stv, bv = ax;
    float safeb = (fabsf(bv) < 1e-6f) ? 1e-6f : bv;
    float dv = a / safeb;
    float md = a - safeb * floorf(dv);
    float sh = fminf(fmaxf(bv, 0.0f), 31.0f);
    float eq = eq_gate_d(a - bv);
    float lt = sigmoidf_(20.0f * (bv - a - 0.5f));
    float gt = sigmoidf_(20.0f * (a - bv - 0.5f));
    float gsum = 0.0f, acc = 0.0f, pop = 0.0f, g;
    g = eq_gate_d(opc - 1.0f);  gsum += g; acc += g * imm;
    g = eq_gate_d(opc - 2.0f);  gsum += g; acc += g * (bp + imm);
    g = eq_gate_d(opc - 9.0f);  gsum += g; acc += g * (a + bv);          pop += g;
    g = eq_gate_d(opc - 10.0f); gsum += g; acc += g * (a - bv);          pop += g;
    g = eq_gate_d(opc - 11.0f); gsum += g; acc += g * (a * bv);          pop += g;
    g = eq_gate_d(opc - 12.0f); gsum += g; acc += g * dv;                pop += g;
    g = eq_gate_d(opc - 13.0f); gsum += g; acc += g * md;                pop += g;
    g = eq_gate_d(opc - 14.0f); gsum += g; acc += g * (a * exp2f(sh));   pop += g;
    g = eq_gate_d(opc - 15.0f); gsum += g; acc += g * (a * exp2f(-sh));  pop += g;
    g = eq_gate_d(opc - 3.0f);  gsum += g; acc += g * eq;                pop += g;
    g = eq_gate_d(opc - 4.0f);  gsum += g; acc += g * (1.0f - eq);       pop += g;
    g = eq_gate_d(opc - 5.0f);  gsum += g; acc += g * lt;                pop += g;
    g = eq_gate_d(opc - 6.0f);  gsum += g; acc += g * gt;                pop += g;
    g = eq_gate_d(opc - 7.0f);  gsum += g; acc += g * (1.0f - gt);       pop += g;
    g = eq_gate_d(opc - 8.0f);  gsum += g; acc += g * (1.0f - lt);       pop += g;
    *pop_out = pop;
    return acc + (1.0f - gsum) * ax;
}

// ---- bulk copy: memory -> d_out ----
__global__ void copy_kernel(const float4* __restrict__ src,
                            float4* __restrict__ dst, int n4) {
    int i = blockIdx.x * blockDim.x + threadIdx.x;
    if (i < n4) dst[i] = src[i];
}

// ---- per-row sim (runs AFTER copy; wrow already holds the memory image) ----
// Fast path: 2 parallel gather rounds via LDS-staged arrays.
// Slow path (hazard rows): direct sequential RMW on wrow — memory IS the
// log (round-1 verified arithmetic). No ws log, no overlay scans.
__global__ void __launch_bounds__(TPB, 1)
sim_kernel(const float* __restrict__ mem,
           float* __restrict__ out,
           const float* __restrict__ outp,
           const float* __restrict__ ax_in,
           const int* __restrict__ pc_in,
           const int* __restrict__ sp_in,
           const int* __restrict__ bp_in,
           const int* __restrict__ ol_in,
           const int* __restrict__ nstep,
           int B) {
    __shared__ float s_raw[TPB][MAXT + 1];
    __shared__ float s_spA[TPB][MAXT + 1];
    __shared__ int   s_tgt[TPB][MAXT + 1];
    __shared__ float s_svr[TPB][MAXT + 1];
    __shared__ float s_lvv[TPB][MAXT + 1];

    int tid = threadIdx.x;
    int b = blockIdx.x * TPB + tid;
    if (b >= B) return;

    const float* __restrict__ mrow = mem + (size_t)b * MEMSZ;
    float* __restrict__ wrow = out + (size_t)b * MEMSZ;
    const float* __restrict__ orow = outp + (size_t)b * 64;

    float pc0 = (float)pc_in[b];
    float sp0 = (float)sp_in[b];
    float bp0 = (float)bp_in[b];
    float ax0 = ax_in[b];
    float olf = (float)ol_in[b];
    int T = nstep[0];

    bool slow = (T > MAXT) || (T < 0);

    if (!slow) {
        // prefetch all instruction loads (pc chain is static) — 16 parallel
#pragma unroll
        for (int t = 0; t < MAXT; ++t) {
            if (t < T) {
                int ai = (int)clipaddr(pc0 + 8.0f * t);
                int ia = (ai < MEMSZ) ? ai : ai - MEMSZ;
                s_raw[tid][t] = mrow[ia];
            }
        }
        // pass A: opcode -> pop -> sp chain -> targets (ALU + LDS only)
        float spc = sp0;
#pragma unroll
        for (int t = 0; t < MAXT; ++t) {
            if (t < T) {
                int ai = (int)clipaddr(pc0 + 8.0f * t);
                int ia = (ai < MEMSZ) ? ai : ai - MEMSZ;
#pragma unroll
                for (int j = 0; j < MAXT; ++j)
                    if (j < t && s_tgt[tid][j] == ia) slow = true;  // RAW hazard
                float inst;
                if (ai < MEMSZ) {
                    inst = s_raw[tid][t];
                } else {
                    int r = ai - MEMSZ;
                    if (r == 3) slow = true;                        // needs ax chain
                    float cv = regval(r, pc0 + 8.0f * t, spc, bp0, 0.0f, olf, orow);
                    inst = 0.5f * (cv + s_raw[tid][t]);
                }
                float imm = floorf(inst * (1.0f / 256.0f));
                float opc = inst - imm * 256.0f;
                float popv = pop_of(opc);
                s_spA[tid][t] = spc;
                int si = (int)clipaddr(spc);
                s_tgt[tid][t] = (si < MEMSZ) ? si : si - MEMSZ;
                spc = spc + 8.0f * popv;
            }
        }
    }

    if (!slow) {
        // pass B: all stack-top loads in parallel
#pragma unroll
        for (int t = 0; t < MAXT; ++t)
            if (t < T) s_svr[tid][t] = mrow[s_tgt[tid][t]];
        // pass C: ax chain + experts + direct in-order writes
        float ax = ax0;
#pragma unroll
        for (int t = 0; t < MAXT; ++t) {
            if (t < T) {
                int ai = (int)clipaddr(pc0 + 8.0f * t);
                float inst;
                if (ai < MEMSZ) {
                    inst = s_raw[tid][t];
                } else {
                    int r = ai - MEMSZ;
                    float cv = regval(r, pc0 + 8.0f * t, s_spA[tid][t], bp0, ax, olf, orow);
                    inst = 0.5f * (cv + s_raw[tid][t]);
                }
                float imm = floorf(inst * (1.0f / 256.0f));
                float opc = inst - imm * 256.0f;
                float mtv = s_svr[tid][t];
                int tg = s_tgt[tid][t];
#pragma unroll
                for (int j = 0; j < MAXT; ++j)
                    if (j < t && s_tgt[tid][j] == tg) mtv = s_lvv[tid][j];  // overlay
                int si = (int)clipaddr(s_spA[tid][t]);
                float stv, wf;
                if (si < MEMSZ) {
                    stv = mtv; wf = 1.0f;
                } else {
                    int r = si - MEMSZ;
                    float cv = regval(r, pc0 + 8.0f * t, s_spA[tid][t], bp0, ax, olf, orow);
                    stv = 0.5f * (cv + mtv); wf = 0.5f;
                }
                float pop;
                float nax = step_update(stv, ax, imm, bp0, opc, &pop);
                float val = mtv + pop * wf * (nax - mtv);
                s_lvv[tid][t] = val;
                wrow[tg] = val;     // in-order per-thread stores: last write wins
                ax = nax;
            }
        }
    } else {
        // slow path: sequential RMW directly on wrow (copy already there).
        // Same-thread program order makes memory itself the write log.
        // Only 1-2 lanes per wave active here -> cheap single-line gathers.
        float pc = pc0, sp = sp0, ax = ax0;
        for (int t = 0; t < T; ++t) {
            int ai = (int)clipaddr(pc);
            float inst;
            if (ai < MEMSZ) {
                inst = wrow[ai];
            } else {
                int r = ai - MEMSZ;
                float cv = regval(r, pc, sp, bp0, ax, olf, orow);
                inst = 0.5f * (cv + wrow[ai - MEMSZ]);
            }
            float imm = floorf(inst * (1.0f / 256.0f));
            float opc = inst - imm * 256.0f;
            int si = (int)clipaddr(sp);
            int tg = (si < MEMSZ) ? si : si - MEMSZ;
            float mtv = wrow[tg];
            float stv, wf;
            if (si < MEMSZ) {
                stv = mtv; wf = 1.0f;
            } else {
                int r = si - MEMSZ;
                float cv = regval(r, pc, sp, bp0, ax, olf, orow);
                stv = 0.5f * (cv + mtv); wf = 0.5f;
            }
            float pop;
            float nax = step_update(stv, ax, imm, bp0, opc, &pop);
            wrow[tg] = mtv + pop * wf * (nax - mtv);
            sp = sp + 8.0f * pop;
            pc = pc + 8.0f;
            ax = nax;
        }
    }
}

extern "C" void kernel_launch(void* const* d_in, const int* in_sizes, int n_in,
                              void* d_out, int out_size, void* d_ws, size_t ws_size,
                              hipStream_t stream) {
    const float* memory = (const float*)d_in[0];
    const float* output = (const float*)d_in[1];
    const float* ax     = (const float*)d_in[2];
    const int*   pc     = (const int*)d_in[3];
    const int*   sp     = (const int*)d_in[4];
    const int*   bp     = (const int*)d_in[5];
    const int*   ol     = (const int*)d_in[6];
    const int*   ns     = (const int*)d_in[7];

    int B = in_sizes[0] / MEMSZ;
    int n4 = B * MEMSZ / 4;

    float* out = (float*)d_out;

    hipLaunchKernelGGL(copy_kernel, dim3((n4 + 255) / 256), dim3(256), 0, stream,
                       (const float4*)memory, (float4*)out, n4);
    hipLaunchKernelGGL(sim_kernel, dim3((B + TPB - 1) / TPB), dim3(TPB), 0, stream,
                       memory, out, output, ax, pc, sp, bp, ol, ns, B);
}